// Round 6
// baseline (172.412 us; speedup 1.0000x reference)
//
#include <hip/hip_runtime.h>

// Geometry (compile-time, from reference)
constexpr int Bn = 8, Dn = 64, Hn = 128, Wn = 64;
constexpr int sH = Wn;                 // 64
constexpr int sD = Hn * Wn;            // 8192
constexpr int sC = Dn * sD;            // 524288
constexpr int sB = 4 * sC;             // 2097152

// Grid spacings
constexpr double DXd = 2.5 / 63.0;
constexpr double DYd = 1.0 / 127.0;
constexpr double DZd = 0.8 / 63.0;

constexpr float I2DX = (float)(0.5 / DXd);
constexpr float I2DY = (float)(0.5 / DYd);
constexpr float I2DZ = (float)(0.5 / DZd);
constexpr float IDX2 = (float)(1.0 / (DXd * DXd));
constexpr float IDY2 = (float)(1.0 / (DYd * DYd));
constexpr float IDZ2 = (float)(1.0 / (DZd * DZd));
constexpr float INV_RE = 1.0e-6f;

// weights / counts
constexpr float CF  = (float)(1.0  / (8.0 * 4.0 * 64.0 * 128.0 * 64.0));
constexpr float CCT = (float)(10.0 / 8.0);
constexpr float CCM = (float)(1.0  / (8.0 * 62.0 * 126.0 * 62.0));
constexpr float CN  = (float)(10.0 / (8.0 * 64.0 * 128.0 * 64.0));
constexpr float CI  = (float)(5.0  / (8.0 * 64.0 * 128.0));
constexpr float CO  = (float)(1.0  / (8.0 * 64.0 * 128.0));

__device__ __forceinline__ float4 ld4(const float* __restrict__ p, int off) {
    return *reinterpret_cast<const float4*>(p + off);
}

// z-march with FULL distance-1 prefetch: every operand of plane d was loaded
// during iteration d-1. Block (16,8)=128 thr (2 waves), 8-plane segments,
// 1024 blocks (4 blocks/CU, 8 waves/CU).
__global__ __launch_bounds__(128, 2) void fno3d_main(
    const float* __restrict__ field,
    const float* __restrict__ gt_field,
    const float* __restrict__ sdf,
    float* __restrict__ partials)
{
    const int x   = threadIdx.x;            // 0..15
    const int ty  = threadIdx.y;            // 0..7
    const int blk = blockIdx.x;             // 0..1023
    const int b   = blk >> 7;               // 8 batches
    const int rem = blk & 127;
    const int d0  = (rem >> 4) << 3;        // 8 segments of 8 planes
    const int h   = ((rem & 15) << 3) + ty; // 16 h-tiles of 8 rows
    const int w0  = x << 2;

    const float* Fb = field    + b * sB;
    const float* Gb = gt_field + b * sB;
    const float* Sb = sdf      + b * sC;

    const int hm = (h > 0)      ? h - 1 : h;
    const int hp = (h < Hn - 1) ? h + 1 : h;
    const bool hIn = (h >= 1) & (h <= Hn - 2);

    const int rowc = h  * sH + w0;
    const int rowm = hm * sH + w0;
    const int rowp = hp * sH + w0;

    // ---- prologue: everything needed for plane d0 ----
    const int dm0 = (d0 > 0) ? d0 - 1 : 0;
    const int dn0 = (d0 < Dn - 1) ? d0 + 1 : d0;

    float4 pU = ld4(Fb, dm0 * sD + rowc);
    float4 pV = ld4(Fb, sC + dm0 * sD + rowc);
    float4 pW = ld4(Fb, 2 * sC + dm0 * sD + rowc);
    float4 pP = ld4(Fb, 3 * sC + dm0 * sD + rowc);
    float4 cU = ld4(Fb, d0 * sD + rowc);
    float4 cV = ld4(Fb, sC + d0 * sD + rowc);
    float4 cW = ld4(Fb, 2 * sC + d0 * sD + rowc);
    float4 cP = ld4(Fb, 3 * sC + d0 * sD + rowc);
    float4 nU = ld4(Fb, dn0 * sD + rowc);
    float4 nV = ld4(Fb, sC + dn0 * sD + rowc);
    float4 nW = ld4(Fb, 2 * sC + dn0 * sD + rowc);
    float4 nP = ld4(Fb, 3 * sC + dn0 * sD + rowc);

    float4 yUm = ld4(Fb, d0 * sD + rowm), yUp = ld4(Fb, d0 * sD + rowp);
    float4 yVm = ld4(Fb, sC + d0 * sD + rowm), yVp = ld4(Fb, sC + d0 * sD + rowp);
    float4 yWm = ld4(Fb, 2 * sC + d0 * sD + rowm), yWp = ld4(Fb, 2 * sC + d0 * sD + rowp);
    float4 yPm = ld4(Fb, 3 * sC + d0 * sD + rowm), yPp = ld4(Fb, 3 * sC + d0 * sD + rowp);

    float4 gU = ld4(Gb, d0 * sD + rowc);
    float4 gV = ld4(Gb, sC + d0 * sD + rowc);
    float4 gW = ld4(Gb, 2 * sC + d0 * sD + rowc);
    float4 gP = ld4(Gb, 3 * sC + d0 * sD + rowc);
    float4 sS = ld4(Sb, d0 * sD + rowc);

    float acc = 0.f;

    #pragma unroll
    for (int k = 0; k < 8; ++k) {
        const int d   = d0 + k;
        const int dn  = (d  < Dn - 1) ? d  + 1 : d;   // next plane (for y±,gt,sdf)
        const int dnn = (dn < Dn - 1) ? dn + 1 : dn;  // plane d+2 (centers)

        // ---- issue ALL next-iteration loads up front (17 x dwordx4) ----
        const float4 qU = ld4(Fb, dnn * sD + rowc);
        const float4 qV = ld4(Fb, sC + dnn * sD + rowc);
        const float4 qW = ld4(Fb, 2 * sC + dnn * sD + rowc);
        const float4 qP = ld4(Fb, 3 * sC + dnn * sD + rowc);

        const float4 zUm = ld4(Fb, dn * sD + rowm), zUp = ld4(Fb, dn * sD + rowp);
        const float4 zVm = ld4(Fb, sC + dn * sD + rowm), zVp = ld4(Fb, sC + dn * sD + rowp);
        const float4 zWm = ld4(Fb, 2 * sC + dn * sD + rowm), zWp = ld4(Fb, 2 * sC + dn * sD + rowp);
        const float4 zPm = ld4(Fb, 3 * sC + dn * sD + rowm), zPp = ld4(Fb, 3 * sC + dn * sD + rowp);

        const float4 hGU = ld4(Gb, dn * sD + rowc);
        const float4 hGV = ld4(Gb, sC + dn * sD + rowc);
        const float4 hGW = ld4(Gb, 2 * sC + dn * sD + rowc);
        const float4 hGP = ld4(Gb, 3 * sC + dn * sD + rowc);
        const float4 hS  = ld4(Sb, dn * sD + rowc);

        // ---- x-neighbors across lanes (held registers only) ----
        const float uLs = __shfl_up(cU.w, 1), uRs = __shfl_down(cU.x, 1);
        const float vLs = __shfl_up(cV.w, 1), vRs = __shfl_down(cV.x, 1);
        const float wLs = __shfl_up(cW.w, 1), wRs = __shfl_down(cW.x, 1);
        const float pLs = __shfl_up(cP.w, 1), pRs = __shfl_down(cP.x, 1);

        const float* au = (const float*)&cU; const float* av = (const float*)&cV;
        const float* aw = (const float*)&cW; const float* ap = (const float*)&cP;
        const float* apu = (const float*)&pU; const float* apv = (const float*)&pV;
        const float* apw = (const float*)&pW; const float* app = (const float*)&pP;
        const float* anu = (const float*)&nU; const float* anv = (const float*)&nV;
        const float* anw = (const float*)&nW; const float* anp = (const float*)&nP;
        const float* agu = (const float*)&gU; const float* agv = (const float*)&gV;
        const float* agw = (const float*)&gW; const float* agp = (const float*)&gP;
        const float* as_ = (const float*)&sS;
        const float* ayum = (const float*)&yUm; const float* ayup = (const float*)&yUp;
        const float* ayvm = (const float*)&yVm; const float* ayvp = (const float*)&yVp;
        const float* aywm = (const float*)&yWm; const float* aywp = (const float*)&yWp;
        const float* aypm = (const float*)&yPm; const float* aypp = (const float*)&yPp;

        const bool dIn = (d >= 1) & (d <= Dn - 2);

        #pragma unroll
        for (int e = 0; e < 4; ++e) {
            const int w = w0 + e;
            const float u = au[e], v = av[e], wq = aw[e], pq = ap[e];

            // field MSE
            {
                const float e0 = u  - agu[e];
                const float e1 = v  - agv[e];
                const float e2 = wq - agw[e];
                const float e3 = pq - agp[e];
                acc += CF * (e0 * e0 + e1 * e1 + e2 * e2 + e3 * e3);
            }

            const float s = as_[e];

            // no-slip (solid)
            acc += ((s <= 0.f) ? CN : 0.f) * (u * u + v * v + wq * wq);

            // inlet (w==0)
            {
                const float du = u - 1.0f;
                acc += ((w == 0) ? CI : 0.f) * (du * du + v * v + wq * wq);
            }

            // interior continuity + momentum
            const float uxm = (e == 0) ? uLs : au[e - 1];
            const float uxp = (e == 3) ? uRs : au[e + 1];
            const float vxm = (e == 0) ? vLs : av[e - 1];
            const float vxp = (e == 3) ? vRs : av[e + 1];
            const float wxm = (e == 0) ? wLs : aw[e - 1];
            const float wxp = (e == 3) ? wRs : aw[e + 1];
            const float pxm = (e == 0) ? pLs : ap[e - 1];
            const float pxp = (e == 3) ? pRs : ap[e + 1];

            const float du_dx = (uxp - uxm) * I2DX;
            const float du_dy = (ayup[e] - ayum[e]) * I2DY;
            const float du_dz = (anu[e] - apu[e]) * I2DZ;
            const float dv_dx = (vxp - vxm) * I2DX;
            const float dv_dy = (ayvp[e] - ayvm[e]) * I2DY;
            const float dv_dz = (anv[e] - apv[e]) * I2DZ;
            const float dw_dx = (wxp - wxm) * I2DX;
            const float dw_dy = (aywp[e] - aywm[e]) * I2DY;
            const float dw_dz = (anw[e] - apw[e]) * I2DZ;
            const float dp_dx = (pxp - pxm) * I2DX;
            const float dp_dy = (aypp[e] - aypm[e]) * I2DY;
            const float dp_dz = (anp[e] - app[e]) * I2DZ;

            const float div = du_dx + dv_dy + dw_dz;

            const float lap_u = (uxp - 2.f * u  + uxm) * IDX2 + (ayup[e] - 2.f * u  + ayum[e]) * IDY2 + (anu[e] - 2.f * u  + apu[e]) * IDZ2;
            const float lap_v = (vxp - 2.f * v  + vxm) * IDX2 + (ayvp[e] - 2.f * v  + ayvm[e]) * IDY2 + (anv[e] - 2.f * v  + apv[e]) * IDZ2;
            const float lap_w = (wxp - 2.f * wq + wxm) * IDX2 + (aywp[e] - 2.f * wq + aywm[e]) * IDY2 + (anw[e] - 2.f * wq + apw[e]) * IDZ2;

            const float rx = u * du_dx + v * du_dy + wq * du_dz + dp_dx - INV_RE * lap_u;
            const float ry = u * dv_dx + v * dv_dy + wq * dv_dz + dp_dy - INV_RE * lap_v;
            const float rz = u * dw_dx + v * dw_dy + wq * dw_dz + dp_dz - INV_RE * lap_w;

            const bool wIn = (w >= 1) & (w <= Wn - 2);
            const float m = (s > 0.f && wIn && hIn && dIn) ? CCM : 0.f;
            acc += m * (div * div + rx * rx + ry * ry + rz * rz);
        }

        // outlet (w==63 vs w==62, lane x==15)
        if (x == 15) {
            const float a0 = au[3] - au[2];
            const float a1 = av[3] - av[2];
            const float a2 = aw[3] - aw[2];
            acc += CO * (a0 * a0 + a1 * a1 + a2 * a2);
        }

        // ---- rotate: prefetched regs become next iteration's operands ----
        pU = cU; pV = cV; pW = cW; pP = cP;
        cU = nU; cV = nV; cW = nW; cP = nP;
        nU = qU; nV = qV; nW = qW; nP = qP;
        yUm = zUm; yUp = zUp; yVm = zVm; yVp = zVp;
        yWm = zWm; yWp = zWp; yPm = zPm; yPp = zPp;
        gU = hGU; gV = hGV; gW = hGW; gP = hGP;
        sS = hS;
    }

    // reduce 2 waves -> one partial per block (no atomics)
    for (int off = 32; off > 0; off >>= 1)
        acc += __shfl_down(acc, off);

    __shared__ float wsum[2];
    const int tid  = threadIdx.y * 16 + threadIdx.x;
    const int wid  = tid >> 6;
    const int lane = tid & 63;
    if (lane == 0) wsum[wid] = acc;
    __syncthreads();
    if (tid == 0) partials[blk] = wsum[0] + wsum[1];
}

// Final reduce: 1024 partials + ct term -> out[0]
__global__ __launch_bounds__(256) void fno3d_reduce(
    const float* __restrict__ partials,
    const float* __restrict__ ct,
    const float* __restrict__ gt_ct,
    float* __restrict__ out)
{
    const int t = threadIdx.x;
    float s = partials[t] + partials[t + 256] + partials[t + 512] + partials[t + 768];
    for (int off = 32; off > 0; off >>= 1)
        s += __shfl_down(s, off);

    __shared__ float wsum[4];
    if ((t & 63) == 0) wsum[t >> 6] = s;
    __syncthreads();
    if (t == 0) {
        float tot = wsum[0] + wsum[1] + wsum[2] + wsum[3];
        float ctl = 0.f;
        for (int i = 0; i < Bn; ++i) {
            const float dc = ct[i] - gt_ct[i];
            ctl += dc * dc;
        }
        out[0] = tot + CCT * ctl;
    }
}

extern "C" void kernel_launch(void* const* d_in, const int* in_sizes, int n_in,
                              void* d_out, int out_size, void* d_ws, size_t ws_size,
                              hipStream_t stream) {
    const float* field    = (const float*)d_in[0];
    const float* ct       = (const float*)d_in[1];
    const float* gt_field = (const float*)d_in[2];
    const float* gt_ct    = (const float*)d_in[3];
    const float* sdf      = (const float*)d_in[4];
    float* out      = (float*)d_out;
    float* partials = (float*)d_ws;   // 1024 floats = 4 KiB of scratch

    hipLaunchKernelGGL(fno3d_main, dim3(1024), dim3(16, 8, 1), 0, stream,
                       field, gt_field, sdf, partials);
    hipLaunchKernelGGL(fno3d_reduce, dim3(1), dim3(256), 0, stream,
                       partials, ct, gt_ct, out);
}